// Round 9
// baseline (249.941 us; speedup 1.0000x reference)
//
#include <hip/hip_runtime.h>
#include <hip/hip_fp16.h>

// Problem geometry (fixed by reference)
#define WINS 7
#define H 160
#define W 160
#define DD 96
#define HO 154          // H - WINS + 1
#define WO 154
#define DOUT 90
#define CSTRIDE (H*W*DD)   // per-(b,c) channel stride

// Tile: 8x8x16 outputs, all 4 classes per block (y staged once, 2-bit packed)
#define TH 8
#define TW 8
#define TD 16
#define IH 14            // TH + WINS - 1
#define IW 14
#define NCOL (IH * IW)   // 196
#define IDU 22           // used d extent = TD + WINS - 1 (even)
#define NDP 11           // dd-pairs per column
#define ID 24            // staged d extent per column (halfs; 6 x half4)
#define NV 6             // half4-items per column
#define NITEMS (NCOL * NV)   // 1176
#define HTILES 20
#define WTILES 20
#define DTILES 6
#define DPB2 24          // sb plane dd-stride in halfs (even, >=22)

struct alignas(8) Half4 { __half x, y, z, w; };

static __device__ __forceinline__ __half2 u2h(unsigned int a) {
    __half2 r; __builtin_memcpy(&r, &a, 4); return r;
}
static __device__ __forceinline__ unsigned int h2u(__half2 v) {
    unsigned int r; __builtin_memcpy(&r, &v, 4); return r;
}
// p = max(v,0) per half; m = (v>0 or v==+0 padding) ? 1.0h : 0.0h per half.
// v = +sigma (mask on), -sigma (mask off), or +0 (padding; feeds only
// discarded outputs dg>=DOUT, so m=1 there is harmless).
static __device__ __forceinline__ void pmask(__half2 v, __half2& p, __half2& m) {
    const unsigned int bits = h2u(v);
    const unsigned int neg  = bits & 0x80008000u;
    const unsigned int full = (neg >> 15) * 0xFFFFu;          // 0xFFFF where negative
    p = u2h(bits & ~full);
    m = u2h(((~bits >> 15) & 0x00010001u) * 0x3C00u);         // 1.0h where sign clear
}

__device__ __forceinline__ float sval(float c0, float c1, float c2) {
    // c0=S_m, c1=S_tm, c2=S_t2m over the 343-voxel window; t = m?sigmoid:0.5
    const float S_t  = c1 + 0.5f  * (343.0f - c0);
    const float S_t2 = c2 + 0.25f * (343.0f - c0);
    const float inv  = 1.0f / 343.0f;
    const float ux   = S_t  * inv;
    const float uy   = c0   * inv;
    const float uxx  = S_t2 * inv;
    const float uxy  = c1   * inv;
    const float covn = 49.0f / 48.0f;   // WIN^2/(WIN^2-1)
    const float cc   = 0.00045f;        // (0.03*data_range)^2/2, data_range==1
    const float vx  = covn * (uxx - ux * ux);
    const float vy  = covn * (uy  - uy * uy);
    const float vxy = covn * (uxy - ux * uy);
    // den >= ~3e-4 always (cc=4.5e-4); fast rcp is safe
    return (vxy + cc) * __builtin_amdgcn_rcpf(vx * vy + cc);
}

__global__ __launch_bounds__(256, 6)
void structure_loss_main(const float* __restrict__ x,
                         const int* __restrict__ y,
                         double* __restrict__ acc) {
    // W-window sums, f16 SoA planes [ih][wo][dd]: 3 * 14*8*22*2 = 14,784 B
    __shared__ __half sA0[IH * TW * IDU];
    __shared__ __half sA1[IH * TW * IDU];
    __shared__ __half sA2[IH * TW * IDU];
    // vs (phase 0/A input) and sb (phase B/C) never live together: 9,408 B
    __shared__ union alignas(16) {
        __half vs[NCOL * ID];            // v = (y==cl ? +sig : -sig), f16
        struct {
            __half b0[TH * TW * DPB2];   // S_m   H-window sums
            __half b1[TH * TW * DPB2];   // S_tm
            __half b2[TH * TW * DPB2];   // S_t2m
        } sb;
    } u;
    __shared__ unsigned int yb[NCOL * 2];   // 2-bit classes, 12 d per u32: 1,568 B
    __shared__ float wsum[4];
    // total ~25.8 KB -> 6 blocks/CU

    const int dt = blockIdx.x;                 // 0..5
    const int wt = blockIdx.y;                 // 0..19
    const int z  = blockIdx.z;                 // 0..39 = b*HTILES + ht
    const int b  = z / HTILES;
    const int ht = z - b * HTILES;

    const int h0 = ht * TH, w0 = wt * TW, d0 = dt * TD;
    const int* yc = y + (size_t)b * (size_t)CSTRIDE;
    const int t = threadIdx.x;

    // ---- Hoisted staging addresses (class-invariant) ----
    int goff[5], lidx[5], yinfo[5];
#pragma unroll
    for (int k = 0; k < 5; k++) {
        const int i = t + 256 * k;
        goff[k] = -1; lidx[k] = 0; yinfo[k] = 0;
        if (i < NITEMS) {
            const int col = i / NV, q = i - col * NV;
            const int ih = col / IW, iw = col - ih * IW;
            const int h = min(h0 + ih, H - 1);
            const int w = min(w0 + iw, W - 1);
            const int dbase = d0 + 4 * q;
            lidx[k] = col * ID + 4 * q;
            const int wsel = (q >= 3) ? 1 : 0;
            yinfo[k] = (col * 2 + wsel) | ((8 * (q - 3 * wsel)) << 16);
            if (dbase < DD) goff[k] = (h * W + w) * DD + dbase;
        }
    }

    // ---- Phase Y: stage y tile 2-bit packed, once (reused by all 4 classes) ----
    for (int i = t; i < NCOL * 2; i += 256) {       // 392 words
        const int col = i >> 1, hf = i & 1;
        const int ih = col / IW, iw = col - ih * IW;
        const int h = min(h0 + ih, H - 1);
        const int w = min(w0 + iw, W - 1);
        const size_t cb = (size_t)(h * W + w) * DD;
        const int dstart = d0 + 12 * hf;
        unsigned int pk = 0u;                       // OOB d: bits 0, but phase 0
#pragma unroll                                      // never consults them (goff<0)
        for (int j3 = 0; j3 < 3; j3++) {
            const int dbase = dstart + 4 * j3;
            if (dbase < DD) {
                const int4 yv = *(const int4*)(yc + cb + dbase);
                pk |= (unsigned)(yv.x & 3) << (2 * (4 * j3 + 0));
                pk |= (unsigned)(yv.y & 3) << (2 * (4 * j3 + 1));
                pk |= (unsigned)(yv.z & 3) << (2 * (4 * j3 + 2));
                pk |= (unsigned)(yv.w & 3) << (2 * (4 * j3 + 3));
            }
        }
        yb[i] = pk;
    }
    __syncthreads();

    float lsum = 0.f;

    for (int cl = 0; cl < 4; cl++) {
        const float* xc = x + ((size_t)b * 4 + cl) * (size_t)CSTRIDE;

        // ---- Phase 0: stage x channel, fuse with staged y. sign bit = mask ----
#pragma unroll
        for (int k = 0; k < 5; k++) {
            const int i = t + 256 * k;
            if (i < NITEMS) {
                Half4 hv;
                hv.x = hv.y = hv.z = hv.w = __float2half(0.f);
                if (goff[k] >= 0) {
                    const float4 xv = *(const float4*)(xc + goff[k]);
                    const unsigned int info = (unsigned)yinfo[k];
                    const unsigned int pk = yb[info & 0xffffu] >> (info >> 16);
                    const float s0 = 1.0f / (1.0f + __expf(-xv.x));
                    const float s1 = 1.0f / (1.0f + __expf(-xv.y));
                    const float s2 = 1.0f / (1.0f + __expf(-xv.z));
                    const float s3 = 1.0f / (1.0f + __expf(-xv.w));
                    hv.x = __float2half(((int)((pk >> 0) & 3u) == cl) ? s0 : -s0);
                    hv.y = __float2half(((int)((pk >> 2) & 3u) == cl) ? s1 : -s1);
                    hv.z = __float2half(((int)((pk >> 4) & 3u) == cl) ? s2 : -s2);
                    hv.w = __float2half(((int)((pk >> 6) & 3u) == cl) ? s3 : -s3);
                }
                *(Half4*)&u.vs[lidx[k]] = hv;
            }
        }
        __syncthreads();

        // ---- Phase A: W-window, packed f16 over dd-pairs. 154 items (ih,dp) ----
        if (t < IH * NDP) {
            const int ih = t / NDP, dp = t - ih * NDP;
            const int dd = 2 * dp;
            const __half2 z2 = __float2half2_rn(0.f);
            __half2 v2[IW];
            const int vbase = ih * IW * ID + dd;
#pragma unroll
            for (int iw = 0; iw < IW; iw++)
                v2[iw] = *(const __half2*)&u.vs[vbase + iw * ID];
            __half2 sm = z2, sp = z2, sq = z2;
#pragma unroll
            for (int iw = 0; iw < WINS; iw++) {
                __half2 p, m;
                pmask(v2[iw], p, m);
                sm = __hadd2(sm, m);
                sp = __hadd2(sp, p);
                sq = __hfma2(p, v2[iw], sq);
            }
            int o = (ih * TW) * IDU + dd;
            *(__half2*)&sA0[o] = sm;
            *(__half2*)&sA1[o] = sp;
            *(__half2*)&sA2[o] = sq;
#pragma unroll
            for (int wo = 1; wo < TW; wo++) {
                const __half2 a = v2[wo + 6], bb = v2[wo - 1];
                __half2 pa, ma, pb, mb;
                pmask(a, pa, ma);
                pmask(bb, pb, mb);
                sm = __hadd2(sm, __hsub2(ma, mb));
                sp = __hadd2(sp, __hsub2(pa, pb));
                sq = __hadd2(sq, __hsub2(__hmul2(pa, a), __hmul2(pb, bb)));
                o += IDU;
                *(__half2*)&sA0[o] = sm;
                *(__half2*)&sA1[o] = sp;
                *(__half2*)&sA2[o] = sq;
            }
        }
        __syncthreads();   // sA ready; vs reads retired before sb overwrites union

        // ---- Phase B: H-window, packed f16 over dd-pairs. 176 items ----
        if (t < 2 * TW * NDP) {
            const int dp = t % NDP;
            const int r  = t / NDP;
            const int wo = r & 7;
            const int ho0 = (r >> 3) * 4;          // 0 or 4
            const int dd = 2 * dp;
            __half2 a0[10], a1[10], a2[10];
#pragma unroll
            for (int k = 0; k < 10; k++) {
                const int idx = ((ho0 + k) * TW + wo) * IDU + dd;
                a0[k] = *(const __half2*)&sA0[idx];
                a1[k] = *(const __half2*)&sA1[idx];
                a2[k] = *(const __half2*)&sA2[idx];
            }
            __half2 s0 = a0[0], s1 = a1[0], s2 = a2[0];
#pragma unroll
            for (int k = 1; k < WINS; k++) {
                s0 = __hadd2(s0, a0[k]);
                s1 = __hadd2(s1, a1[k]);
                s2 = __hadd2(s2, a2[k]);
            }
            int o = (ho0 * TW + wo) * DPB2 + dd;
            *(__half2*)&u.sb.b0[o] = s0;
            *(__half2*)&u.sb.b1[o] = s1;
            *(__half2*)&u.sb.b2[o] = s2;
#pragma unroll
            for (int k = 1; k < 4; k++) {
                s0 = __hadd2(s0, __hsub2(a0[k + 6], a0[k - 1]));
                s1 = __hadd2(s1, __hsub2(a1[k + 6], a1[k - 1]));
                s2 = __hadd2(s2, __hsub2(a2[k + 6], a2[k - 1]));
                o += TW * DPB2;
                *(__half2*)&u.sb.b0[o] = s0;
                *(__half2*)&u.sb.b1[o] = s1;
                *(__half2*)&u.sb.b2[o] = s2;
            }
        }
        __syncthreads();

        // ---- Phase C: D-window, slide 4 outputs. 256 threads (ho,wo,dq) ----
        {
            const int dq = t & 3;                  // d outputs dq*4 .. dq*4+3
            const int wo = (t >> 2) & 7;
            const int ho = t >> 5;
            const int hg = h0 + ho, wg = w0 + wo;
            if (hg < HO && wg < WO) {
                const int base = (ho * TW + wo) * DPB2 + dq * 4;   // even -> aligned
                float b0[10], b1[10], b2[10];
#pragma unroll
                for (int k = 0; k < 5; k++) {
                    float2 f;
                    f = __half22float2(*(const __half2*)&u.sb.b0[base + 2 * k]);
                    b0[2 * k] = f.x; b0[2 * k + 1] = f.y;
                    f = __half22float2(*(const __half2*)&u.sb.b1[base + 2 * k]);
                    b1[2 * k] = f.x; b1[2 * k + 1] = f.y;
                    f = __half22float2(*(const __half2*)&u.sb.b2[base + 2 * k]);
                    b2[2 * k] = f.x; b2[2 * k + 1] = f.y;
                }
                float s0 = 0.f, s1 = 0.f, s2 = 0.f;
#pragma unroll
                for (int k = 0; k < WINS; k++) { s0 += b0[k]; s1 += b1[k]; s2 += b2[k]; }
                const int dg = d0 + dq * 4;
#pragma unroll
                for (int k = 0; k < 4; k++) {
                    if (k > 0) {
                        s0 += b0[k + 6] - b0[k - 1];
                        s1 += b1[k + 6] - b1[k - 1];
                        s2 += b2[k + 6] - b2[k - 1];
                    }
                    if (dg + k < DOUT) lsum += sval(s0, s1, s2);
                }
            }
        }
        __syncthreads();   // retire sb reads before next class overwrites union
    }

    // wave(64) shuffle reduce, then cross-wave via LDS, one atomic per block
#pragma unroll
    for (int off = 32; off > 0; off >>= 1) lsum += __shfl_down(lsum, off, 64);
    const int wave = t >> 6;
    if ((t & 63) == 0) wsum[wave] = lsum;
    __syncthreads();
    if (t == 0) {
        const float s = wsum[0] + wsum[1] + wsum[2] + wsum[3];
        atomicAdd(acc, (double)s);
    }
}

__global__ void structure_loss_finalize(const double* __restrict__ acc,
                                        float* __restrict__ out) {
    out[0] = 1.0f - (float)(acc[0] / 17075520.0);   // 8*154*154*90
}

extern "C" void kernel_launch(void* const* d_in, const int* in_sizes, int n_in,
                              void* d_out, int out_size, void* d_ws, size_t ws_size,
                              hipStream_t stream) {
    const float* x = (const float*)d_in[0];
    const int*   y = (const int*)d_in[1];
    double* acc = (double*)d_ws;

    (void)hipMemsetAsync(d_ws, 0, sizeof(double), stream);

    dim3 grid(DTILES, WTILES, 2 * HTILES);   // (6, 20, 40) = 4,800 blocks
    structure_loss_main<<<grid, 256, 0, stream>>>(x, y, acc);
    structure_loss_finalize<<<1, 1, 0, stream>>>(acc, (float*)d_out);
}

// Round 10
// 246.739 us; speedup vs baseline: 1.0130x; 1.0130x over previous
//
#include <hip/hip_runtime.h>
#include <hip/hip_fp16.h>

// Problem geometry (fixed by reference)
#define WINS 7
#define H 160
#define W 160
#define DD 96
#define HO 154          // H - WINS + 1
#define WO 154
#define DOUT 90
#define CSTRIDE (H*W*DD)   // per-(b,c) channel stride

// Tile: 8x8x16 outputs, all 4 classes per block (y staged once, 2-bit packed)
#define TH 8
#define TW 8
#define TD 16
#define IH 14            // TH + WINS - 1
#define IW 14
#define NCOL (IH * IW)   // 196
#define IDU 22           // used d extent = TD + WINS - 1 (even)
#define NDP 11           // dd-pairs per column
#define ID 24            // staged d extent per column (halfs; 6 x half4)
#define NV 6             // half4-items per column
#define NITEMS (NCOL * NV)   // 1176
#define HTILES 20
#define WTILES 20
#define DTILES 6
#define DPB2 24          // sb plane dd-stride in halfs (even, >=22)

struct alignas(8) Half4 { __half x, y, z, w; };

static __device__ __forceinline__ __half2 u2h(unsigned int a) {
    __half2 r; __builtin_memcpy(&r, &a, 4); return r;
}
static __device__ __forceinline__ unsigned int h2u(__half2 v) {
    unsigned int r; __builtin_memcpy(&r, &v, 4); return r;
}
// p = max(v,0) per half; m = (sign clear) ? 1.0h : 0.0h per half.
// v = +sigma (mask on), -sigma (mask off), or +0 (padding; feeds only
// discarded outputs dg>=DOUT, so m=1 there is harmless).
static __device__ __forceinline__ void pmask(__half2 v, __half2& p, __half2& m) {
    const unsigned int bits = h2u(v);
    const unsigned int neg  = bits & 0x80008000u;
    const unsigned int full = (neg >> 15) * 0xFFFFu;          // 0xFFFF where negative
    p = u2h(bits & ~full);
    m = u2h(((~bits >> 15) & 0x00010001u) * 0x3C00u);         // 1.0h where sign clear
}

__device__ __forceinline__ float sval(float c0, float c1, float c2) {
    // c0=S_m, c1=S_tm, c2=S_t2m over the 343-voxel window; t = m?sigmoid:0.5
    const float S_t  = c1 + 0.5f  * (343.0f - c0);
    const float S_t2 = c2 + 0.25f * (343.0f - c0);
    const float inv  = 1.0f / 343.0f;
    const float ux   = S_t  * inv;
    const float uy   = c0   * inv;
    const float uxx  = S_t2 * inv;
    const float uxy  = c1   * inv;
    const float covn = 49.0f / 48.0f;   // WIN^2/(WIN^2-1)
    const float cc   = 0.00045f;        // (0.03*data_range)^2/2, data_range==1
    const float vx  = covn * (uxx - ux * ux);
    const float vy  = covn * (uy  - uy * uy);
    const float vxy = covn * (uxy - ux * uy);
    // den >= ~3e-4 always (cc=4.5e-4); fast rcp is safe
    return (vxy + cc) * __builtin_amdgcn_rcpf(vx * vy + cc);
}

__global__ __launch_bounds__(256, 6)
void structure_loss_main(const float* __restrict__ x,
                         const int* __restrict__ y,
                         double* __restrict__ acc) {
    // W-window sums, f16 SoA planes [ih][wo][dd]: 3 * 14*8*22*2 = 14,784 B
    __shared__ __half sA0[IH * TW * IDU];
    __shared__ __half sA1[IH * TW * IDU];
    __shared__ __half sA2[IH * TW * IDU];
    // vs (phase 0/A input) and sb (phase B/C) never live together: 9,408 B
    __shared__ union alignas(16) {
        __half vs[NCOL * ID];            // v = (y==cl ? +sig : -sig), f16
        struct {
            __half b0[TH * TW * DPB2];   // S_m   H-window sums
            __half b1[TH * TW * DPB2];   // S_tm
            __half b2[TH * TW * DPB2];   // S_t2m
        } sb;
    } u;
    __shared__ unsigned int yb[NCOL * 2];   // 2-bit classes, 12 d per u32: 1,568 B
    __shared__ float wsum[4];
    // total ~25.8 KB -> 6 blocks/CU (VGPR must stay <=~80: no persistent arrays!)

    const int dt = blockIdx.x;                 // 0..5
    const int wt = blockIdx.y;                 // 0..19
    const int z  = blockIdx.z;                 // 0..39 = b*HTILES + ht
    const int b  = z / HTILES;
    const int ht = z - b * HTILES;

    const int h0 = ht * TH, w0 = wt * TW, d0 = dt * TD;
    const int* yc = y + (size_t)b * (size_t)CSTRIDE;
    const int t = threadIdx.x;

    // ---- Phase Y: stage y tile 2-bit packed, once (reused by all 4 classes) ----
    for (int i = t; i < NCOL * 2; i += 256) {       // 392 words
        const int col = i >> 1, hf = i & 1;
        const int ih = col / IW, iw = col - ih * IW;
        const int h = min(h0 + ih, H - 1);
        const int w = min(w0 + iw, W - 1);
        const size_t cb = (size_t)(h * W + w) * DD;
        const int dstart = d0 + 12 * hf;
        unsigned int pk = 0u;                       // OOB d: bits 0; phase 0 never
#pragma unroll                                      // consults them (dbase>=DD)
        for (int j3 = 0; j3 < 3; j3++) {
            const int dbase = dstart + 4 * j3;
            if (dbase < DD) {
                const int4 yv = *(const int4*)(yc + cb + dbase);
                pk |= (unsigned)(yv.x & 3) << (2 * (4 * j3 + 0));
                pk |= (unsigned)(yv.y & 3) << (2 * (4 * j3 + 1));
                pk |= (unsigned)(yv.z & 3) << (2 * (4 * j3 + 2));
                pk |= (unsigned)(yv.w & 3) << (2 * (4 * j3 + 3));
            }
        }
        yb[i] = pk;
    }
    __syncthreads();

    float lsum = 0.f;

    for (int cl = 0; cl < 4; cl++) {
        const float* xc = x + ((size_t)b * 4 + cl) * (size_t)CSTRIDE;

        // ---- Phase 0: stage x channel, fuse with staged y. sign bit = mask ----
        // Addresses recomputed per class (cheap int ops; hoisting them into
        // per-thread arrays spilled to scratch at 6 waves/EU -- R9 regression).
#pragma unroll
        for (int k = 0; k < 5; k++) {
            const int i = t + 256 * k;
            if (i < NITEMS) {
                const int col = i / NV, q = i - col * NV;
                const int ih = col / IW, iw = col - ih * IW;
                const int h = min(h0 + ih, H - 1);
                const int w = min(w0 + iw, W - 1);
                const int dbase = d0 + 4 * q;
                Half4 hv;
                hv.x = hv.y = hv.z = hv.w = __float2half(0.f);
                if (dbase < DD) {
                    const float4 xv = *(const float4*)(xc + (h * W + w) * DD + dbase);
                    const int wsel = (q >= 3) ? 1 : 0;
                    const unsigned int pk =
                        yb[col * 2 + wsel] >> (8 * (q - 3 * wsel));
                    const float s0 = 1.0f / (1.0f + __expf(-xv.x));
                    const float s1 = 1.0f / (1.0f + __expf(-xv.y));
                    const float s2 = 1.0f / (1.0f + __expf(-xv.z));
                    const float s3 = 1.0f / (1.0f + __expf(-xv.w));
                    hv.x = __float2half(((int)((pk >> 0) & 3u) == cl) ? s0 : -s0);
                    hv.y = __float2half(((int)((pk >> 2) & 3u) == cl) ? s1 : -s1);
                    hv.z = __float2half(((int)((pk >> 4) & 3u) == cl) ? s2 : -s2);
                    hv.w = __float2half(((int)((pk >> 6) & 3u) == cl) ? s3 : -s3);
                }
                *(Half4*)&u.vs[col * ID + 4 * q] = hv;
            }
        }
        __syncthreads();

        // ---- Phase A: W-window, packed f16 over dd-pairs. 154 items (ih,dp) ----
        if (t < IH * NDP) {
            const int ih = t / NDP, dp = t - ih * NDP;
            const int dd = 2 * dp;
            const __half2 z2 = __float2half2_rn(0.f);
            __half2 v2[IW];
            const int vbase = ih * IW * ID + dd;
#pragma unroll
            for (int iw = 0; iw < IW; iw++)
                v2[iw] = *(const __half2*)&u.vs[vbase + iw * ID];
            __half2 sm = z2, sp = z2, sq = z2;
#pragma unroll
            for (int iw = 0; iw < WINS; iw++) {
                __half2 p, m;
                pmask(v2[iw], p, m);
                sm = __hadd2(sm, m);
                sp = __hadd2(sp, p);
                sq = __hfma2(p, v2[iw], sq);
            }
            int o = (ih * TW) * IDU + dd;
            *(__half2*)&sA0[o] = sm;
            *(__half2*)&sA1[o] = sp;
            *(__half2*)&sA2[o] = sq;
#pragma unroll
            for (int wo = 1; wo < TW; wo++) {
                const __half2 a = v2[wo + 6], bb = v2[wo - 1];
                __half2 pa, ma, pb, mb;
                pmask(a, pa, ma);
                pmask(bb, pb, mb);
                sm = __hadd2(sm, __hsub2(ma, mb));
                sp = __hadd2(sp, __hsub2(pa, pb));
                sq = __hadd2(sq, __hsub2(__hmul2(pa, a), __hmul2(pb, bb)));
                o += IDU;
                *(__half2*)&sA0[o] = sm;
                *(__half2*)&sA1[o] = sp;
                *(__half2*)&sA2[o] = sq;
            }
        }
        __syncthreads();   // sA ready; vs reads retired before sb overwrites union

        // ---- Phase B: H-window, packed f16 over dd-pairs. 176 items ----
        if (t < 2 * TW * NDP) {
            const int dp = t % NDP;
            const int r  = t / NDP;
            const int wo = r & 7;
            const int ho0 = (r >> 3) * 4;          // 0 or 4
            const int dd = 2 * dp;
            __half2 a0[10], a1[10], a2[10];
#pragma unroll
            for (int k = 0; k < 10; k++) {
                const int idx = ((ho0 + k) * TW + wo) * IDU + dd;
                a0[k] = *(const __half2*)&sA0[idx];
                a1[k] = *(const __half2*)&sA1[idx];
                a2[k] = *(const __half2*)&sA2[idx];
            }
            __half2 s0 = a0[0], s1 = a1[0], s2 = a2[0];
#pragma unroll
            for (int k = 1; k < WINS; k++) {
                s0 = __hadd2(s0, a0[k]);
                s1 = __hadd2(s1, a1[k]);
                s2 = __hadd2(s2, a2[k]);
            }
            int o = (ho0 * TW + wo) * DPB2 + dd;
            *(__half2*)&u.sb.b0[o] = s0;
            *(__half2*)&u.sb.b1[o] = s1;
            *(__half2*)&u.sb.b2[o] = s2;
#pragma unroll
            for (int k = 1; k < 4; k++) {
                s0 = __hadd2(s0, __hsub2(a0[k + 6], a0[k - 1]));
                s1 = __hadd2(s1, __hsub2(a1[k + 6], a1[k - 1]));
                s2 = __hadd2(s2, __hsub2(a2[k + 6], a2[k - 1]));
                o += TW * DPB2;
                *(__half2*)&u.sb.b0[o] = s0;
                *(__half2*)&u.sb.b1[o] = s1;
                *(__half2*)&u.sb.b2[o] = s2;
            }
        }
        __syncthreads();

        // ---- Phase C: D-window, slide 4 outputs. 256 threads (ho,wo,dq) ----
        {
            const int dq = t & 3;                  // d outputs dq*4 .. dq*4+3
            const int wo = (t >> 2) & 7;
            const int ho = t >> 5;
            const int hg = h0 + ho, wg = w0 + wo;
            if (hg < HO && wg < WO) {
                const int base = (ho * TW + wo) * DPB2 + dq * 4;   // even -> aligned
                float b0[10], b1[10], b2[10];
#pragma unroll
                for (int k = 0; k < 5; k++) {
                    float2 f;
                    f = __half22float2(*(const __half2*)&u.sb.b0[base + 2 * k]);
                    b0[2 * k] = f.x; b0[2 * k + 1] = f.y;
                    f = __half22float2(*(const __half2*)&u.sb.b1[base + 2 * k]);
                    b1[2 * k] = f.x; b1[2 * k + 1] = f.y;
                    f = __half22float2(*(const __half2*)&u.sb.b2[base + 2 * k]);
                    b2[2 * k] = f.x; b2[2 * k + 1] = f.y;
                }
                float s0 = 0.f, s1 = 0.f, s2 = 0.f;
#pragma unroll
                for (int k = 0; k < WINS; k++) { s0 += b0[k]; s1 += b1[k]; s2 += b2[k]; }
                const int dg = d0 + dq * 4;
#pragma unroll
                for (int k = 0; k < 4; k++) {
                    if (k > 0) {
                        s0 += b0[k + 6] - b0[k - 1];
                        s1 += b1[k + 6] - b1[k - 1];
                        s2 += b2[k + 6] - b2[k - 1];
                    }
                    if (dg + k < DOUT) lsum += sval(s0, s1, s2);
                }
            }
        }
        __syncthreads();   // retire sb reads before next class overwrites union
    }

    // wave(64) shuffle reduce, then cross-wave via LDS, one atomic per block
#pragma unroll
    for (int off = 32; off > 0; off >>= 1) lsum += __shfl_down(lsum, off, 64);
    const int wave = t >> 6;
    if ((t & 63) == 0) wsum[wave] = lsum;
    __syncthreads();
    if (t == 0) {
        const float s = wsum[0] + wsum[1] + wsum[2] + wsum[3];
        atomicAdd(acc, (double)s);
    }
}

__global__ void structure_loss_finalize(const double* __restrict__ acc,
                                        float* __restrict__ out) {
    out[0] = 1.0f - (float)(acc[0] / 17075520.0);   // 8*154*154*90
}

extern "C" void kernel_launch(void* const* d_in, const int* in_sizes, int n_in,
                              void* d_out, int out_size, void* d_ws, size_t ws_size,
                              hipStream_t stream) {
    const float* x = (const float*)d_in[0];
    const int*   y = (const int*)d_in[1];
    double* acc = (double*)d_ws;

    (void)hipMemsetAsync(d_ws, 0, sizeof(double), stream);

    dim3 grid(DTILES, WTILES, 2 * HTILES);   // (6, 20, 40) = 4,800 blocks
    structure_loss_main<<<grid, 256, 0, stream>>>(x, y, acc);
    structure_loss_finalize<<<1, 1, 0, stream>>>(acc, (float*)d_out);
}

// Round 11
// 220.982 us; speedup vs baseline: 1.1310x; 1.1166x over previous
//
#include <hip/hip_runtime.h>
#include <hip/hip_fp16.h>

// Problem geometry (fixed by reference)
#define WINS 7
#define H 160
#define W 160
#define DD 96
#define HO 154          // H - WINS + 1
#define WO 154
#define DOUT 90
#define CSTRIDE (H*W*DD)   // per-(b,c) channel stride

// Tile: 8x8x16 outputs, all 4 classes per block (y staged once, 2-bit packed)
#define TH 8
#define TW 8
#define TD 16
#define IH 14            // TH + WINS - 1
#define IW 14
#define NCOL (IH * IW)   // 196
#define IDU 22           // used d extent = TD + WINS - 1 (even)
#define NDP 11           // dd-pairs per column
#define ID 24            // staged d extent per column (halfs; 6 x half4)
#define NV 6             // half4-items per column
#define NITEMS (NCOL * NV)   // 1176
#define HTILES 20
#define WTILES 20
#define DTILES 6
#define DPB2 24          // sb plane dd-stride in halfs (even, >=22)

struct alignas(8) Half4 { __half x, y, z, w; };

static __device__ __forceinline__ __half2 u2h(unsigned int a) {
    __half2 r; __builtin_memcpy(&r, &a, 4); return r;
}
static __device__ __forceinline__ unsigned int h2u(__half2 v) {
    unsigned int r; __builtin_memcpy(&r, &v, 4); return r;
}
// p = max(v,0) per half; m = (sign clear) ? 1.0h : 0.0h per half.
// v = +sigma (mask on), -sigma (mask off), or +0 (padding; feeds only
// discarded outputs dg>=DOUT, so m=1 there is harmless).
static __device__ __forceinline__ void pmask(__half2 v, __half2& p, __half2& m) {
    const unsigned int bits = h2u(v);
    const unsigned int neg  = bits & 0x80008000u;
    const unsigned int full = (neg >> 15) * 0xFFFFu;          // 0xFFFF where negative
    p = u2h(bits & ~full);
    m = u2h(((~bits >> 15) & 0x00010001u) * 0x3C00u);         // 1.0h where sign clear
}

__device__ __forceinline__ float sval(float c0, float c1, float c2) {
    // c0=S_m, c1=S_tm, c2=S_t2m over the 343-voxel window; t = m?sigmoid:0.5
    const float S_t  = c1 + 0.5f  * (343.0f - c0);
    const float S_t2 = c2 + 0.25f * (343.0f - c0);
    const float inv  = 1.0f / 343.0f;
    const float ux   = S_t  * inv;
    const float uy   = c0   * inv;
    const float uxx  = S_t2 * inv;
    const float uxy  = c1   * inv;
    const float covn = 49.0f / 48.0f;   // WIN^2/(WIN^2-1)
    const float cc   = 0.00045f;        // (0.03*data_range)^2/2, data_range==1
    const float vx  = covn * (uxx - ux * ux);
    const float vy  = covn * (uy  - uy * uy);
    const float vxy = covn * (uxy - ux * uy);
    // den >= ~3e-4 always (cc=4.5e-4); fast rcp is safe
    return (vxy + cc) * __builtin_amdgcn_rcpf(vx * vy + cc);
}

// (256,5): R9/R10's (256,6) pinned the allocator to 40 VGPR -> 57.75 MB of
// scratch spill per dispatch. (256,5) gives the allocator ~100 VGPR headroom
// (R7: 44 VGPR, zero spill on this code shape); HW occupancy is then
// LDS-capped at 6 blocks/CU (25.8 KB), same as R9's target.
__global__ __launch_bounds__(256, 5)
void structure_loss_main(const float* __restrict__ x,
                         const int* __restrict__ y,
                         double* __restrict__ acc) {
    // W-window sums, f16 SoA planes [ih][wo][dd]: 3 * 14*8*22*2 = 14,784 B
    __shared__ __half sA0[IH * TW * IDU];
    __shared__ __half sA1[IH * TW * IDU];
    __shared__ __half sA2[IH * TW * IDU];
    // vs (phase 0/A input) and sb (phase B/C) never live together: 9,408 B
    __shared__ union alignas(16) {
        __half vs[NCOL * ID];            // v = (y==cl ? +sig : -sig), f16
        struct {
            __half b0[TH * TW * DPB2];   // S_m   H-window sums
            __half b1[TH * TW * DPB2];   // S_tm
            __half b2[TH * TW * DPB2];   // S_t2m
        } sb;
    } u;
    __shared__ unsigned int yb[NCOL * 2];   // 2-bit classes, 12 d per u32: 1,568 B
    __shared__ float wsum[4];
    // total ~25.8 KB -> 6 blocks/CU

    const int dt = blockIdx.x;                 // 0..5
    const int wt = blockIdx.y;                 // 0..19
    const int z  = blockIdx.z;                 // 0..39 = b*HTILES + ht
    const int b  = z / HTILES;
    const int ht = z - b * HTILES;

    const int h0 = ht * TH, w0 = wt * TW, d0 = dt * TD;
    const int* yc = y + (size_t)b * (size_t)CSTRIDE;
    const int t = threadIdx.x;

    // ---- Phase Y: stage y tile 2-bit packed, once (reused by all 4 classes) ----
    for (int i = t; i < NCOL * 2; i += 256) {       // 392 words
        const int col = i >> 1, hf = i & 1;
        const int ih = col / IW, iw = col - ih * IW;
        const int h = min(h0 + ih, H - 1);
        const int w = min(w0 + iw, W - 1);
        const size_t cb = (size_t)(h * W + w) * DD;
        const int dstart = d0 + 12 * hf;
        unsigned int pk = 0u;                       // OOB d: bits 0; phase 0 never
#pragma unroll                                      // consults them (dbase>=DD)
        for (int j3 = 0; j3 < 3; j3++) {
            const int dbase = dstart + 4 * j3;
            if (dbase < DD) {
                const int4 yv = *(const int4*)(yc + cb + dbase);
                pk |= (unsigned)(yv.x & 3) << (2 * (4 * j3 + 0));
                pk |= (unsigned)(yv.y & 3) << (2 * (4 * j3 + 1));
                pk |= (unsigned)(yv.z & 3) << (2 * (4 * j3 + 2));
                pk |= (unsigned)(yv.w & 3) << (2 * (4 * j3 + 3));
            }
        }
        yb[i] = pk;
    }
    __syncthreads();

    float lsum = 0.f;

    for (int cl = 0; cl < 4; cl++) {
        const float* xc = x + ((size_t)b * 4 + cl) * (size_t)CSTRIDE;

        // ---- Phase 0: stage x channel, fuse with staged y. sign bit = mask ----
#pragma unroll
        for (int k = 0; k < 5; k++) {
            const int i = t + 256 * k;
            if (i < NITEMS) {
                const int col = i / NV, q = i - col * NV;
                const int ih = col / IW, iw = col - ih * IW;
                const int h = min(h0 + ih, H - 1);
                const int w = min(w0 + iw, W - 1);
                const int dbase = d0 + 4 * q;
                Half4 hv;
                hv.x = hv.y = hv.z = hv.w = __float2half(0.f);
                if (dbase < DD) {
                    const float4 xv = *(const float4*)(xc + (h * W + w) * DD + dbase);
                    const int wsel = (q >= 3) ? 1 : 0;
                    const unsigned int pk =
                        yb[col * 2 + wsel] >> (8 * (q - 3 * wsel));
                    const float s0 = 1.0f / (1.0f + __expf(-xv.x));
                    const float s1 = 1.0f / (1.0f + __expf(-xv.y));
                    const float s2 = 1.0f / (1.0f + __expf(-xv.z));
                    const float s3 = 1.0f / (1.0f + __expf(-xv.w));
                    hv.x = __float2half(((int)((pk >> 0) & 3u) == cl) ? s0 : -s0);
                    hv.y = __float2half(((int)((pk >> 2) & 3u) == cl) ? s1 : -s1);
                    hv.z = __float2half(((int)((pk >> 4) & 3u) == cl) ? s2 : -s2);
                    hv.w = __float2half(((int)((pk >> 6) & 3u) == cl) ? s3 : -s3);
                }
                *(Half4*)&u.vs[col * ID + 4 * q] = hv;
            }
        }
        __syncthreads();

        // ---- Phase A: W-window, packed f16 over dd-pairs. 154 items (ih,dp) ----
        if (t < IH * NDP) {
            const int ih = t / NDP, dp = t - ih * NDP;
            const int dd = 2 * dp;
            const __half2 z2 = __float2half2_rn(0.f);
            __half2 v2[IW];
            const int vbase = ih * IW * ID + dd;
#pragma unroll
            for (int iw = 0; iw < IW; iw++)
                v2[iw] = *(const __half2*)&u.vs[vbase + iw * ID];
            __half2 sm = z2, sp = z2, sq = z2;
#pragma unroll
            for (int iw = 0; iw < WINS; iw++) {
                __half2 p, m;
                pmask(v2[iw], p, m);
                sm = __hadd2(sm, m);
                sp = __hadd2(sp, p);
                sq = __hfma2(p, v2[iw], sq);
            }
            int o = (ih * TW) * IDU + dd;
            *(__half2*)&sA0[o] = sm;
            *(__half2*)&sA1[o] = sp;
            *(__half2*)&sA2[o] = sq;
#pragma unroll
            for (int wo = 1; wo < TW; wo++) {
                const __half2 a = v2[wo + 6], bb = v2[wo - 1];
                __half2 pa, ma, pb, mb;
                pmask(a, pa, ma);
                pmask(bb, pb, mb);
                sm = __hadd2(sm, __hsub2(ma, mb));
                sp = __hadd2(sp, __hsub2(pa, pb));
                sq = __hadd2(sq, __hsub2(__hmul2(pa, a), __hmul2(pb, bb)));
                o += IDU;
                *(__half2*)&sA0[o] = sm;
                *(__half2*)&sA1[o] = sp;
                *(__half2*)&sA2[o] = sq;
            }
        }
        __syncthreads();   // sA ready; vs reads retired before sb overwrites union

        // ---- Phase B: H-window, packed f16 over dd-pairs. 176 items ----
        if (t < 2 * TW * NDP) {
            const int dp = t % NDP;
            const int r  = t / NDP;
            const int wo = r & 7;
            const int ho0 = (r >> 3) * 4;          // 0 or 4
            const int dd = 2 * dp;
            __half2 a0[10], a1[10], a2[10];
#pragma unroll
            for (int k = 0; k < 10; k++) {
                const int idx = ((ho0 + k) * TW + wo) * IDU + dd;
                a0[k] = *(const __half2*)&sA0[idx];
                a1[k] = *(const __half2*)&sA1[idx];
                a2[k] = *(const __half2*)&sA2[idx];
            }
            __half2 s0 = a0[0], s1 = a1[0], s2 = a2[0];
#pragma unroll
            for (int k = 1; k < WINS; k++) {
                s0 = __hadd2(s0, a0[k]);
                s1 = __hadd2(s1, a1[k]);
                s2 = __hadd2(s2, a2[k]);
            }
            int o = (ho0 * TW + wo) * DPB2 + dd;
            *(__half2*)&u.sb.b0[o] = s0;
            *(__half2*)&u.sb.b1[o] = s1;
            *(__half2*)&u.sb.b2[o] = s2;
#pragma unroll
            for (int k = 1; k < 4; k++) {
                s0 = __hadd2(s0, __hsub2(a0[k + 6], a0[k - 1]));
                s1 = __hadd2(s1, __hsub2(a1[k + 6], a1[k - 1]));
                s2 = __hadd2(s2, __hsub2(a2[k + 6], a2[k - 1]));
                o += TW * DPB2;
                *(__half2*)&u.sb.b0[o] = s0;
                *(__half2*)&u.sb.b1[o] = s1;
                *(__half2*)&u.sb.b2[o] = s2;
            }
        }
        __syncthreads();

        // ---- Phase C: D-window, slide 4 outputs. 256 threads (ho,wo,dq) ----
        {
            const int dq = t & 3;                  // d outputs dq*4 .. dq*4+3
            const int wo = (t >> 2) & 7;
            const int ho = t >> 5;
            const int hg = h0 + ho, wg = w0 + wo;
            if (hg < HO && wg < WO) {
                const int base = (ho * TW + wo) * DPB2 + dq * 4;   // even -> aligned
                float b0[10], b1[10], b2[10];
#pragma unroll
                for (int k = 0; k < 5; k++) {
                    float2 f;
                    f = __half22float2(*(const __half2*)&u.sb.b0[base + 2 * k]);
                    b0[2 * k] = f.x; b0[2 * k + 1] = f.y;
                    f = __half22float2(*(const __half2*)&u.sb.b1[base + 2 * k]);
                    b1[2 * k] = f.x; b1[2 * k + 1] = f.y;
                    f = __half22float2(*(const __half2*)&u.sb.b2[base + 2 * k]);
                    b2[2 * k] = f.x; b2[2 * k + 1] = f.y;
                }
                float s0 = 0.f, s1 = 0.f, s2 = 0.f;
#pragma unroll
                for (int k = 0; k < WINS; k++) { s0 += b0[k]; s1 += b1[k]; s2 += b2[k]; }
                const int dg = d0 + dq * 4;
#pragma unroll
                for (int k = 0; k < 4; k++) {
                    if (k > 0) {
                        s0 += b0[k + 6] - b0[k - 1];
                        s1 += b1[k + 6] - b1[k - 1];
                        s2 += b2[k + 6] - b2[k - 1];
                    }
                    if (dg + k < DOUT) lsum += sval(s0, s1, s2);
                }
            }
        }
        __syncthreads();   // retire sb reads before next class overwrites union
    }

    // wave(64) shuffle reduce, then cross-wave via LDS, one atomic per block
#pragma unroll
    for (int off = 32; off > 0; off >>= 1) lsum += __shfl_down(lsum, off, 64);
    const int wave = t >> 6;
    if ((t & 63) == 0) wsum[wave] = lsum;
    __syncthreads();
    if (t == 0) {
        const float s = wsum[0] + wsum[1] + wsum[2] + wsum[3];
        atomicAdd(acc, (double)s);
    }
}

__global__ void structure_loss_finalize(const double* __restrict__ acc,
                                        float* __restrict__ out) {
    out[0] = 1.0f - (float)(acc[0] / 17075520.0);   // 8*154*154*90
}

extern "C" void kernel_launch(void* const* d_in, const int* in_sizes, int n_in,
                              void* d_out, int out_size, void* d_ws, size_t ws_size,
                              hipStream_t stream) {
    const float* x = (const float*)d_in[0];
    const int*   y = (const int*)d_in[1];
    double* acc = (double*)d_ws;

    (void)hipMemsetAsync(d_ws, 0, sizeof(double), stream);

    dim3 grid(DTILES, WTILES, 2 * HTILES);   // (6, 20, 40) = 4,800 blocks
    structure_loss_main<<<grid, 256, 0, stream>>>(x, y, acc);
    structure_loss_finalize<<<1, 1, 0, stream>>>(acc, (float*)d_out);
}

// Round 12
// 211.884 us; speedup vs baseline: 1.1796x; 1.0429x over previous
//
#include <hip/hip_runtime.h>
#include <hip/hip_fp16.h>

// Problem geometry (fixed by reference)
#define WINS 7
#define H 160
#define W 160
#define DD 96
#define HO 154          // H - WINS + 1
#define WO 154
#define DOUT 90
#define CSTRIDE (H*W*DD)   // per-(b,c) channel stride

// Tile: 8x8x16 outputs, all 4 classes per block
#define TH 8
#define TW 8
#define TD 16
#define IH 14            // TH + WINS - 1
#define IW 14
#define NCOL (IH * IW)   // 196
#define IDU 22           // used d extent = TD + WINS - 1 (even)
#define NDP 11           // dd-pairs per column
#define ID 24            // staged d extent per column (halfs; 3 x half8)
#define NV 6             // half4-items per column (fallback path)
#define NITEMS (NCOL * NV)   // 1176
#define HTILES 20
#define WTILES 20
#define DTILES 6
#define DPB2 24          // sb plane dd-stride in halfs (even, >=22)

struct alignas(8) Half4 { __half x, y, z, w; };

static __device__ __forceinline__ __half2 u2h(unsigned int a) {
    __half2 r; __builtin_memcpy(&r, &a, 4); return r;
}
static __device__ __forceinline__ unsigned int h2u(__half2 v) {
    unsigned int r; __builtin_memcpy(&r, &v, 4); return r;
}
// p = max(v,0) per half; m = (sign clear) ? 1.0h : 0.0h per half.
// v = +sigma (mask on), -sigma (mask off), or +0 (padding; feeds only
// discarded outputs dg>=DOUT, so m=1 there is harmless).
static __device__ __forceinline__ void pmask(__half2 v, __half2& p, __half2& m) {
    const unsigned int bits = h2u(v);
    const unsigned int neg  = bits & 0x80008000u;
    const unsigned int full = (neg >> 15) * 0xFFFFu;          // 0xFFFF where negative
    p = u2h(bits & ~full);
    m = u2h(((~bits >> 15) & 0x00010001u) * 0x3C00u);         // 1.0h where sign clear
}

__device__ __forceinline__ float sval(float c0, float c1, float c2) {
    // c0=S_m, c1=S_tm, c2=S_t2m over the 343-voxel window; t = m?sigmoid:0.5
    const float S_t  = c1 + 0.5f  * (343.0f - c0);
    const float S_t2 = c2 + 0.25f * (343.0f - c0);
    const float inv  = 1.0f / 343.0f;
    const float ux   = S_t  * inv;
    const float uy   = c0   * inv;
    const float uxx  = S_t2 * inv;
    const float uxy  = c1   * inv;
    const float covn = 49.0f / 48.0f;   // WIN^2/(WIN^2-1)
    const float cc   = 0.00045f;        // (0.03*data_range)^2/2, data_range==1
    const float vx  = covn * (uxx - ux * ux);
    const float vy  = covn * (uy  - uy * uy);
    const float vxy = covn * (uxy - ux * uy);
    return (vxy + cc) * __builtin_amdgcn_rcpf(vx * vy + cc);   // den >= ~3e-4
}

// Pre-pass: v = (y==c ? +sigmoid(x) : -sigmoid(x)) as f16, one value per
// (channel, voxel). Removes the 4.6x halo-amplified transcendental recompute
// from the main kernel (R11: ~35-40us of quarter-rate exp/rcp).
__global__ __launch_bounds__(256)
void sigmoid_prepass(const float* __restrict__ x,
                     const int* __restrict__ y,
                     __half* __restrict__ xs) {
    const int b  = blockIdx.y;
    const int qv = blockIdx.x * 256 + threadIdx.x;    // 0..614399
    const int off = 4 * qv;
    const int4 yv = *(const int4*)(y + (size_t)b * CSTRIDE + off);
#pragma unroll
    for (int c = 0; c < 4; c++) {
        const size_t xo = ((size_t)(b * 4 + c)) * CSTRIDE + off;
        const float4 xv = *(const float4*)(x + xo);
        const float s0 = 1.0f / (1.0f + __expf(-xv.x));
        const float s1 = 1.0f / (1.0f + __expf(-xv.y));
        const float s2 = 1.0f / (1.0f + __expf(-xv.z));
        const float s3 = 1.0f / (1.0f + __expf(-xv.w));
        Half4 hv;
        hv.x = __float2half((yv.x == c) ? s0 : -s0);
        hv.y = __float2half((yv.y == c) ? s1 : -s1);
        hv.z = __float2half((yv.z == c) ? s2 : -s2);
        hv.w = __float2half((yv.w == c) ? s3 : -s3);
        *(Half4*)(xs + xo) = hv;
    }
}

// (256,5): (256,6) pinned the allocator to 40 VGPR -> massive scratch spill
// (R9/R10). (256,5) -> 48 VGPR, zero spill; HW occupancy is LDS-capped.
template <bool PRE>
__global__ __launch_bounds__(256, 5)
void structure_loss_main(const float* __restrict__ x,
                         const int* __restrict__ y,
                         const __half* __restrict__ xs,
                         double* __restrict__ acc) {
    // W-window sums, f16 SoA planes [ih][wo][dd]: 3 * 14*8*22*2 = 14,784 B
    __shared__ __half sA0[IH * TW * IDU];
    __shared__ __half sA1[IH * TW * IDU];
    __shared__ __half sA2[IH * TW * IDU];
    // vs (phase 0/A input) and sb (phase B/C) never live together: 9,408 B
    __shared__ union alignas(16) {
        __half vs[NCOL * ID];            // v = +/- sigma, f16
        struct {
            __half b0[TH * TW * DPB2];   // S_m   H-window sums
            __half b1[TH * TW * DPB2];   // S_tm
            __half b2[TH * TW * DPB2];   // S_t2m
        } sb;
    } u;
    __shared__ unsigned int yb[NCOL * 2];   // fallback only: 2-bit packed y
    __shared__ float wsum[4];

    const int dt = blockIdx.x;                 // 0..5
    const int wt = blockIdx.y;                 // 0..19
    const int z  = blockIdx.z;                 // 0..39 = b*HTILES + ht
    const int b  = z / HTILES;
    const int ht = z - b * HTILES;

    const int h0 = ht * TH, w0 = wt * TW, d0 = dt * TD;
    const int* yc = y + (size_t)b * (size_t)CSTRIDE;
    const int t = threadIdx.x;

    if (!PRE) {
        // ---- Phase Y (fallback): stage y tile 2-bit packed ----
        for (int i = t; i < NCOL * 2; i += 256) {
            const int col = i >> 1, hf = i & 1;
            const int ih = col / IW, iw = col - ih * IW;
            const int h = min(h0 + ih, H - 1);
            const int w = min(w0 + iw, W - 1);
            const size_t cb = (size_t)(h * W + w) * DD;
            const int dstart = d0 + 12 * hf;
            unsigned int pk = 0u;
#pragma unroll
            for (int j3 = 0; j3 < 3; j3++) {
                const int dbase = dstart + 4 * j3;
                if (dbase < DD) {
                    const int4 yv = *(const int4*)(yc + cb + dbase);
                    pk |= (unsigned)(yv.x & 3) << (2 * (4 * j3 + 0));
                    pk |= (unsigned)(yv.y & 3) << (2 * (4 * j3 + 1));
                    pk |= (unsigned)(yv.z & 3) << (2 * (4 * j3 + 2));
                    pk |= (unsigned)(yv.w & 3) << (2 * (4 * j3 + 3));
                }
            }
            yb[i] = pk;
        }
        __syncthreads();
    }

    float lsum = 0.f;

    for (int cl = 0; cl < 4; cl++) {
        if (PRE) {
            // ---- Phase 0 (PRE): pure Half8 copy of precomputed +/-sigma ----
            const __half* xsc = xs + ((size_t)b * 4 + cl) * (size_t)CSTRIDE;
#pragma unroll
            for (int k = 0; k < 3; k++) {              // 588 items, Half8 each
                const int i = t + 256 * k;
                if (i < NCOL * 3) {
                    const int col = i / 3, q = i - col * 3;
                    const int ih = col / IW, iw = col - ih * IW;
                    const int h = min(h0 + ih, H - 1);
                    const int w = min(w0 + iw, W - 1);
                    const int dbase = d0 + 8 * q;
                    uint4 vv = make_uint4(0u, 0u, 0u, 0u);   // +0 padding
                    if (dbase < DD)
                        vv = *(const uint4*)(xsc + (h * W + w) * DD + dbase);
                    *(uint4*)&u.vs[col * ID + 8 * q] = vv;
                }
            }
        } else {
            // ---- Phase 0 (fallback): stage x, compute sigmoid, fuse y ----
            const float* xc = x + ((size_t)b * 4 + cl) * (size_t)CSTRIDE;
#pragma unroll
            for (int k = 0; k < 5; k++) {
                const int i = t + 256 * k;
                if (i < NITEMS) {
                    const int col = i / NV, q = i - col * NV;
                    const int ih = col / IW, iw = col - ih * IW;
                    const int h = min(h0 + ih, H - 1);
                    const int w = min(w0 + iw, W - 1);
                    const int dbase = d0 + 4 * q;
                    Half4 hv;
                    hv.x = hv.y = hv.z = hv.w = __float2half(0.f);
                    if (dbase < DD) {
                        const float4 xv = *(const float4*)(xc + (h * W + w) * DD + dbase);
                        const int wsel = (q >= 3) ? 1 : 0;
                        const unsigned int pk =
                            yb[col * 2 + wsel] >> (8 * (q - 3 * wsel));
                        const float s0 = 1.0f / (1.0f + __expf(-xv.x));
                        const float s1 = 1.0f / (1.0f + __expf(-xv.y));
                        const float s2 = 1.0f / (1.0f + __expf(-xv.z));
                        const float s3 = 1.0f / (1.0f + __expf(-xv.w));
                        hv.x = __float2half(((int)((pk >> 0) & 3u) == cl) ? s0 : -s0);
                        hv.y = __float2half(((int)((pk >> 2) & 3u) == cl) ? s1 : -s1);
                        hv.z = __float2half(((int)((pk >> 4) & 3u) == cl) ? s2 : -s2);
                        hv.w = __float2half(((int)((pk >> 6) & 3u) == cl) ? s3 : -s3);
                    }
                    *(Half4*)&u.vs[col * ID + 4 * q] = hv;
                }
            }
        }
        __syncthreads();

        // ---- Phase A: W-window, packed f16 over dd-pairs. 154 items (ih,dp) ----
        if (t < IH * NDP) {
            const int ih = t / NDP, dp = t - ih * NDP;
            const int dd = 2 * dp;
            const __half2 z2 = __float2half2_rn(0.f);
            __half2 v2[IW];
            const int vbase = ih * IW * ID + dd;
#pragma unroll
            for (int iw = 0; iw < IW; iw++)
                v2[iw] = *(const __half2*)&u.vs[vbase + iw * ID];
            __half2 sm = z2, sp = z2, sq = z2;
#pragma unroll
            for (int iw = 0; iw < WINS; iw++) {
                __half2 p, m;
                pmask(v2[iw], p, m);
                sm = __hadd2(sm, m);
                sp = __hadd2(sp, p);
                sq = __hfma2(p, v2[iw], sq);
            }
            int o = (ih * TW) * IDU + dd;
            *(__half2*)&sA0[o] = sm;
            *(__half2*)&sA1[o] = sp;
            *(__half2*)&sA2[o] = sq;
#pragma unroll
            for (int wo = 1; wo < TW; wo++) {
                const __half2 a = v2[wo + 6], bb = v2[wo - 1];
                __half2 pa, ma, pb, mb;
                pmask(a, pa, ma);
                pmask(bb, pb, mb);
                sm = __hadd2(sm, __hsub2(ma, mb));
                sp = __hadd2(sp, __hsub2(pa, pb));
                sq = __hadd2(sq, __hsub2(__hmul2(pa, a), __hmul2(pb, bb)));
                o += IDU;
                *(__half2*)&sA0[o] = sm;
                *(__half2*)&sA1[o] = sp;
                *(__half2*)&sA2[o] = sq;
            }
        }
        __syncthreads();   // sA ready; vs reads retired before sb overwrites union

        // ---- Phase B: H-window, packed f16 over dd-pairs. 176 items ----
        if (t < 2 * TW * NDP) {
            const int dp = t % NDP;
            const int r  = t / NDP;
            const int wo = r & 7;
            const int ho0 = (r >> 3) * 4;          // 0 or 4
            const int dd = 2 * dp;
            __half2 a0[10], a1[10], a2[10];
#pragma unroll
            for (int k = 0; k < 10; k++) {
                const int idx = ((ho0 + k) * TW + wo) * IDU + dd;
                a0[k] = *(const __half2*)&sA0[idx];
                a1[k] = *(const __half2*)&sA1[idx];
                a2[k] = *(const __half2*)&sA2[idx];
            }
            __half2 s0 = a0[0], s1 = a1[0], s2 = a2[0];
#pragma unroll
            for (int k = 1; k < WINS; k++) {
                s0 = __hadd2(s0, a0[k]);
                s1 = __hadd2(s1, a1[k]);
                s2 = __hadd2(s2, a2[k]);
            }
            int o = (ho0 * TW + wo) * DPB2 + dd;
            *(__half2*)&u.sb.b0[o] = s0;
            *(__half2*)&u.sb.b1[o] = s1;
            *(__half2*)&u.sb.b2[o] = s2;
#pragma unroll
            for (int k = 1; k < 4; k++) {
                s0 = __hadd2(s0, __hsub2(a0[k + 6], a0[k - 1]));
                s1 = __hadd2(s1, __hsub2(a1[k + 6], a1[k - 1]));
                s2 = __hadd2(s2, __hsub2(a2[k + 6], a2[k - 1]));
                o += TW * DPB2;
                *(__half2*)&u.sb.b0[o] = s0;
                *(__half2*)&u.sb.b1[o] = s1;
                *(__half2*)&u.sb.b2[o] = s2;
            }
        }
        __syncthreads();

        // ---- Phase C: D-window, slide 4 outputs. 256 threads (ho,wo,dq) ----
        {
            const int dq = t & 3;                  // d outputs dq*4 .. dq*4+3
            const int wo = (t >> 2) & 7;
            const int ho = t >> 5;
            const int hg = h0 + ho, wg = w0 + wo;
            if (hg < HO && wg < WO) {
                const int base = (ho * TW + wo) * DPB2 + dq * 4;   // even -> aligned
                float b0[10], b1[10], b2[10];
#pragma unroll
                for (int k = 0; k < 5; k++) {
                    float2 f;
                    f = __half22float2(*(const __half2*)&u.sb.b0[base + 2 * k]);
                    b0[2 * k] = f.x; b0[2 * k + 1] = f.y;
                    f = __half22float2(*(const __half2*)&u.sb.b1[base + 2 * k]);
                    b1[2 * k] = f.x; b1[2 * k + 1] = f.y;
                    f = __half22float2(*(const __half2*)&u.sb.b2[base + 2 * k]);
                    b2[2 * k] = f.x; b2[2 * k + 1] = f.y;
                }
                float s0 = 0.f, s1 = 0.f, s2 = 0.f;
#pragma unroll
                for (int k = 0; k < WINS; k++) { s0 += b0[k]; s1 += b1[k]; s2 += b2[k]; }
                const int dg = d0 + dq * 4;
#pragma unroll
                for (int k = 0; k < 4; k++) {
                    if (k > 0) {
                        s0 += b0[k + 6] - b0[k - 1];
                        s1 += b1[k + 6] - b1[k - 1];
                        s2 += b2[k + 6] - b2[k - 1];
                    }
                    if (dg + k < DOUT) lsum += sval(s0, s1, s2);
                }
            }
        }
        __syncthreads();   // retire sb reads before next class overwrites union
    }

    // wave(64) shuffle reduce, then cross-wave via LDS, one atomic per block
#pragma unroll
    for (int off = 32; off > 0; off >>= 1) lsum += __shfl_down(lsum, off, 64);
    const int wave = t >> 6;
    if ((t & 63) == 0) wsum[wave] = lsum;
    __syncthreads();
    if (t == 0) {
        const float s = wsum[0] + wsum[1] + wsum[2] + wsum[3];
        atomicAdd(acc, (double)s);
    }
}

__global__ void structure_loss_finalize(const double* __restrict__ acc,
                                        float* __restrict__ out) {
    out[0] = 1.0f - (float)(acc[0] / 17075520.0);   // 8*154*154*90
}

extern "C" void kernel_launch(void* const* d_in, const int* in_sizes, int n_in,
                              void* d_out, int out_size, void* d_ws, size_t ws_size,
                              hipStream_t stream) {
    const float* x = (const float*)d_in[0];
    const int*   y = (const int*)d_in[1];
    double* acc = (double*)d_ws;
    __half* xs = (__half*)((char*)d_ws + 16);

    (void)hipMemsetAsync(d_ws, 0, sizeof(double), stream);

    const size_t need = 16 + (size_t)8 * CSTRIDE * sizeof(__half);   // ~39.3 MB
    dim3 grid(DTILES, WTILES, 2 * HTILES);   // (6, 20, 40) = 4,800 blocks

    if (ws_size >= need) {
        sigmoid_prepass<<<dim3(2400, 2), 256, 0, stream>>>(x, y, xs);
        structure_loss_main<true><<<grid, 256, 0, stream>>>(x, y, xs, acc);
    } else {
        structure_loss_main<false><<<grid, 256, 0, stream>>>(x, y, xs, acc);
    }
    structure_loss_finalize<<<1, 1, 0, stream>>>(acc, (float*)d_out);
}